// Round 1
// baseline (208.782 us; speedup 1.0000x reference)
//
#include <hip/hip_runtime.h>
#include <hip/hip_bf16.h>

// Problem constants
#define IMG_H 256
#define IMG_W 256
#define N_NODES 8
#define N_EDGES 64
#define CO 64          // conv output channels
#define OH 128         // conv output spatial
#define OW 128
#define PH 64          // pooled spatial
#define PW 64
#define TAPS 147       // 3 * 7 * 7
#define FEAT 1024
#define BN_EPS 1e-5f

// Workspace layout (bytes):
//   wrep   @ 0          : 2*147*64 fp32   = 75,264   (rounded region 128 KB)
//   A      @ 131072     : 8*64*128*128 bf16 = 16,777,216
//   B      @ 16,908,288 : 16,777,216
//   pooled @ 33,685,504 : 64*64 fp32 = 16,384
// total ~33.7 MB
#define OFF_WREP   0
#define OFF_A      131072
#define OFF_B      (131072 + 16777216)
#define OFF_POOLED (131072 + 2*16777216)

// ---------------------------------------------------------------------------
// K0: repack conv1_w [64][6][7][7] -> wrep[h][tap][c]  (tap = ci*49+ky*7+kx,
// ci in 0..2 within half h). Makes per-tap weights contiguous + wave-uniform.
__global__ __launch_bounds__(256) void repack_kernel(
        const float* __restrict__ w, float* __restrict__ wrep) {
    int idx = blockIdx.x * 256 + threadIdx.x;
    if (idx < 2 * TAPS * CO) {
        int c   = idx & 63;
        int tap = (idx >> 6) % TAPS;
        int h   = idx / (TAPS * CO);
        // conv1_w index for (c, cin=h*3+ci, ky, kx) = c*294 + h*147 + tap
        wrep[idx] = w[c * 294 + h * TAPS + tap];
    }
}

// ---------------------------------------------------------------------------
// K1: half-conv. For each (node n, half h), compute 64-channel 7x7 s2 conv of
// 3 input channels -> [64][128][128], stored bf16.
// Grid: 1024 blocks = 16 (n,h) * 64 tiles (8x8 of 16x16 outputs). 256 thr.
__global__ __launch_bounds__(256) void conv_kernel(
        const float* __restrict__ x, const float* __restrict__ wrep,
        __hip_bfloat16* __restrict__ A, __hip_bfloat16* __restrict__ B) {
    int bx   = blockIdx.x;
    int nh   = bx >> 6;            // 0..15
    int n    = nh >> 1;
    int h    = nh & 1;
    int tile = bx & 63;
    int i0   = (tile >> 3) << 4;   // output tile origin
    int j0   = (tile & 7) << 4;

    __shared__ float s_in[3][37][38];   // 37x37 patch, padded cols

    const float* img = x + (size_t)n * (3 * IMG_H * IMG_W);
    int iy0 = 2 * i0 - 3, ix0 = 2 * j0 - 3;
    int t = threadIdx.x;

    for (int idx = t; idx < 3 * 37 * 37; idx += 256) {
        int rx  = idx % 37;
        int tmp = idx / 37;
        int ry  = tmp % 37;
        int ci  = tmp / 37;
        int gy = iy0 + ry, gx = ix0 + rx;
        float v = 0.f;
        if ((unsigned)gy < IMG_H && (unsigned)gx < IMG_W)
            v = img[(ci * IMG_H + gy) * IMG_W + gx];
        s_in[ci][ry][rx] = v;
    }
    __syncthreads();

    float acc[CO];
#pragma unroll
    for (int c = 0; c < CO; ++c) acc[c] = 0.f;

    int ti = t >> 4, tj = t & 15;
    const float* wp = wrep + h * (TAPS * CO);   // uniform base

    for (int ci = 0; ci < 3; ++ci) {
        for (int ky = 0; ky < 7; ++ky) {
#pragma unroll
            for (int kx = 0; kx < 7; ++kx) {
                float iv = s_in[ci][2 * ti + ky][2 * tj + kx];
                const float* wrow = wp + ((ci * 7 + ky) * 7 + kx) * CO;
#pragma unroll
                for (int c = 0; c < CO; ++c)
                    acc[c] = fmaf(iv, wrow[c], acc[c]);   // SGPR weight operand
            }
        }
    }

    int oi = i0 + ti, oj = j0 + tj;
    __hip_bfloat16* dst = (h == 0 ? A : B);
    dst += (size_t)(n * CO) * (OH * OW) + oi * OW + oj;
#pragma unroll
    for (int c = 0; c < CO; ++c)
        dst[c * (OH * OW)] = __float2bfloat16(acc[c]);
}

// ---------------------------------------------------------------------------
// K2: per (edge, channel): z = relu(scale*(A[nmin]+B[nmax])+shift) on the
// 128x128 plane (staged in LDS), maxpool 3x3 s2 pad1 -> 64x64, mean -> pooled.
// Grid: 4096 blocks (e*64+c), 256 threads. LDS: exactly 64 KB.
__global__ __launch_bounds__(256) void pool_kernel(
        const int* __restrict__ ei,
        const float* __restrict__ gamma, const float* __restrict__ beta,
        const float* __restrict__ mean,  const float* __restrict__ var,
        const __hip_bfloat16* __restrict__ A, const __hip_bfloat16* __restrict__ B,
        float* __restrict__ pooled) {
    int b = blockIdx.x;
    int e = b >> 6, c = b & 63;
    int a0 = ei[e], a1 = ei[N_EDGES + e];
    int nmin = min(a0, a1), nmax = max(a0, a1);
    float sc = gamma[c] * rsqrtf(var[c] + BN_EPS);
    float sh = beta[c] - mean[c] * sc;

    __shared__ float z[OH * OW];   // 65536 B

    const uint4* pa = (const uint4*)(A + (size_t)(nmin * CO + c) * (OH * OW));
    const uint4* pb = (const uint4*)(B + (size_t)(nmax * CO + c) * (OH * OW));
    int t = threadIdx.x;

    // 16384 elems = 2048 uint4 (8 bf16 each); 256 threads x 8 iters
#pragma unroll
    for (int it = 0; it < 8; ++it) {
        int vi = it * 256 + t;
        uint4 av = pa[vi];
        uint4 bv = pb[vi];
        float4 lo, hi;
        float* lop = &lo.x;
        float* hip_ = &hi.x;
        const unsigned* au = &av.x;
        const unsigned* bu = &bv.x;
#pragma unroll
        for (int k = 0; k < 4; ++k) {
            float fa0 = __uint_as_float(au[k] << 16);
            float fa1 = __uint_as_float(au[k] & 0xffff0000u);
            float fb0 = __uint_as_float(bu[k] << 16);
            float fb1 = __uint_as_float(bu[k] & 0xffff0000u);
            float z0 = fmaxf(fmaf(sc, fa0 + fb0, sh), 0.f);
            float z1 = fmaxf(fmaf(sc, fa1 + fb1, sh), 0.f);
            if (k < 2) { lop[2 * k] = z0; lop[2 * k + 1] = z1; }
            else       { hip_[2 * (k - 2)] = z0; hip_[2 * (k - 2) + 1] = z1; }
        }
        ((float4*)z)[vi * 2]     = lo;
        ((float4*)z)[vi * 2 + 1] = hi;
    }
    __syncthreads();

    float lsum = 0.f;
#pragma unroll
    for (int k = 0; k < 16; ++k) {
        int pi = k * 256 + t;       // 0..4095
        int p = pi >> 6, q = pi & 63;
        int y0 = 2 * p - 1, x0 = 2 * q - 1;
        float m = 0.f;              // relu>=0 => OOB-as-0 matches -inf-pad max
#pragma unroll
        for (int dy = 0; dy < 3; ++dy) {
            int y = y0 + dy;
            if ((unsigned)y < (unsigned)OH) {
#pragma unroll
                for (int dx = 0; dx < 3; ++dx) {
                    int xx = x0 + dx;
                    if ((unsigned)xx < (unsigned)OW)
                        m = fmaxf(m, z[y * OW + xx]);
                }
            }
        }
        lsum += m;
    }
    // block reduce (reuse z after all reads complete)
#pragma unroll
    for (int off = 32; off > 0; off >>= 1) lsum += __shfl_down(lsum, off, 64);
    __syncthreads();
    if ((t & 63) == 0) z[t >> 6] = lsum;
    __syncthreads();
    if (t == 0) pooled[b] = (z[0] + z[1] + z[2] + z[3]) * (1.f / 4096.f);
}

// ---------------------------------------------------------------------------
// K3: ef = relu(pooled @ fc_w^T + fc_b); heads fused as 6 running dots.
// Grid: 64 blocks (one per edge), 256 threads (4 features each).
__global__ __launch_bounds__(256) void head_kernel(
        const float* __restrict__ pooled,
        const float* __restrict__ fc_w,   const float* __restrict__ fc_b,
        const float* __restrict__ xyz_w,  const float* __restrict__ xyz_b,
        const float* __restrict__ wpqr_w, const float* __restrict__ wpqr_b,
        float* __restrict__ out) {
    int e = blockIdx.x;
    int t = threadIdx.x;
    __shared__ float pl[CO];
    if (t < CO) pl[t] = pooled[e * CO + t];
    __syncthreads();

    float s[6] = {0.f, 0.f, 0.f, 0.f, 0.f, 0.f};
#pragma unroll
    for (int ff = 0; ff < 4; ++ff) {
        int f = ff * 256 + t;
        const float* wr = fc_w + f * CO;
        float d = fc_b[f];
#pragma unroll
        for (int c = 0; c < CO; ++c) d = fmaf(pl[c], wr[c], d);
        d = fmaxf(d, 0.f);
#pragma unroll
        for (int r = 0; r < 3; ++r) {
            s[r]     = fmaf(d, xyz_w[r * FEAT + f],  s[r]);
            s[3 + r] = fmaf(d, wpqr_w[r * FEAT + f], s[3 + r]);
        }
    }
#pragma unroll
    for (int r = 0; r < 6; ++r)
#pragma unroll
        for (int off = 32; off > 0; off >>= 1)
            s[r] += __shfl_down(s[r], off, 64);

    __shared__ float red[4][6];
    if ((t & 63) == 0) {
#pragma unroll
        for (int r = 0; r < 6; ++r) red[t >> 6][r] = s[r];
    }
    __syncthreads();
    if (t < 6) {
        float v = red[0][t] + red[1][t] + red[2][t] + red[3][t];
        v += (t < 3) ? xyz_b[t] : wpqr_b[t - 3];
        out[48 + e * 6 + t] = v;     // full (output 1)
        if (e < 8) out[e * 6 + t] = v;   // full[:8] (output 0)
    }
}

// ---------------------------------------------------------------------------
extern "C" void kernel_launch(void* const* d_in, const int* in_sizes, int n_in,
                              void* d_out, int out_size, void* d_ws, size_t ws_size,
                              hipStream_t stream) {
    const float* x        = (const float*)d_in[0];
    const int*   ei       = (const int*)d_in[1];
    const float* conv1_w  = (const float*)d_in[2];
    const float* bn_gamma = (const float*)d_in[3];
    const float* bn_beta  = (const float*)d_in[4];
    const float* bn_mean  = (const float*)d_in[5];
    const float* bn_var   = (const float*)d_in[6];
    const float* fc_w     = (const float*)d_in[7];
    const float* fc_b     = (const float*)d_in[8];
    const float* xyz_w    = (const float*)d_in[9];
    const float* xyz_b    = (const float*)d_in[10];
    const float* wpqr_w   = (const float*)d_in[11];
    const float* wpqr_b   = (const float*)d_in[12];
    float* out = (float*)d_out;

    char* ws = (char*)d_ws;
    float*           wrep   = (float*)(ws + OFF_WREP);
    __hip_bfloat16*  A      = (__hip_bfloat16*)(ws + OFF_A);
    __hip_bfloat16*  B      = (__hip_bfloat16*)(ws + OFF_B);
    float*           pooled = (float*)(ws + OFF_POOLED);

    repack_kernel<<<(2 * TAPS * CO + 255) / 256, 256, 0, stream>>>(conv1_w, wrep);
    conv_kernel<<<1024, 256, 0, stream>>>(x, wrep, A, B);
    pool_kernel<<<4096, 256, 0, stream>>>(ei, bn_gamma, bn_beta, bn_mean, bn_var,
                                          A, B, pooled);
    head_kernel<<<64, 256, 0, stream>>>(pooled, fc_w, fc_b,
                                        xyz_w, xyz_b, wpqr_w, wpqr_b, out);
}

// Round 2
// 178.066 us; speedup vs baseline: 1.1725x; 1.1725x over previous
//
#include <hip/hip_runtime.h>
#include <hip/hip_bf16.h>

// Problem constants
#define IMG_H 256
#define IMG_W 256
#define N_NODES 8
#define N_EDGES 64
#define CO 64          // conv output channels
#define OH 128         // conv output spatial
#define OW 128
#define TAPS 147       // 3 * 7 * 7
#define FEAT 1024
#define BN_EPS 1e-5f

// Workspace layout (bytes):
//   wrep    @ 0        : 2*147*64 fp32 = 75,264 (region padded to 128 KB)
//   partial @ 0        : 8*64*64 fp32 = 131,072  -- ALIASES wrep: wrep is dead
//                        after conv_kernel; pool writes partial afterwards.
//   A2      @ 131072   : 8*64*128*128 bf16 = 16,777,216   (BN-scaled conv, first 3 ch)
//   B2      @ +16M     : 16,777,216                        (BN-scaled + shifted, last 3 ch)
#define OFF_WREP    0
#define OFF_PARTIAL 0
#define OFF_A       131072
#define OFF_B       (131072 + 16777216)

__device__ __forceinline__ float blo(unsigned u) { return __uint_as_float(u << 16); }
__device__ __forceinline__ float bhi(unsigned u) { return __uint_as_float(u & 0xffff0000u); }

// ---------------------------------------------------------------------------
// K0: repack conv1_w [64][6][7][7] -> wrep[h][tap][c]  (tap = ci*49+ky*7+kx).
// Per-tap weights contiguous across c => wave-uniform s_load in conv.
__global__ __launch_bounds__(256) void repack_kernel(
        const float* __restrict__ w, float* __restrict__ wrep) {
    int idx = blockIdx.x * 256 + threadIdx.x;
    if (idx < 2 * TAPS * CO) {
        int c   = idx & 63;
        int tap = (idx >> 6) % TAPS;
        int h   = idx / (TAPS * CO);
        wrep[idx] = w[c * 294 + h * TAPS + tap];
    }
}

// ---------------------------------------------------------------------------
// K1: half-conv with BN folded into the epilogue.
//   h==0: A2 = scale_c * conv(first-3-ch)       (bf16)
//   h==1: B2 = scale_c * conv(last-3-ch) + shift_c
// Parity-split LDS patch: col x -> [x&1][x>>1]; tap read becomes lane-stride-1
// (2-way bank aliasing only == free). __launch_bounds__(256,1) lets the
// compiler keep acc[64] in VGPRs (no channel-chunking / LDS re-reads).
__global__ __launch_bounds__(256, 1) void conv_kernel(
        const float* __restrict__ x, const float* __restrict__ wrep,
        const float* __restrict__ gamma, const float* __restrict__ beta,
        const float* __restrict__ mean,  const float* __restrict__ var,
        __hip_bfloat16* __restrict__ A2, __hip_bfloat16* __restrict__ B2) {
    int bx   = blockIdx.x;
    int nh   = bx >> 6;            // 0..15
    int n    = nh >> 1;
    int h    = nh & 1;
    int tile = bx & 63;
    int i0   = (tile >> 3) << 4;
    int j0   = (tile & 7) << 4;

    __shared__ float s_in[3][37][2][20];   // 17,760 B, parity-split

    const float* img = x + (size_t)n * (3 * IMG_H * IMG_W);
    int iy0 = 2 * i0 - 3, ix0 = 2 * j0 - 3;
    int t = threadIdx.x;

    for (int idx = t; idx < 3 * 37 * 37; idx += 256) {
        int rx  = idx % 37;
        int tmp = idx / 37;
        int ry  = tmp % 37;
        int ci  = tmp / 37;
        int gy = iy0 + ry, gx = ix0 + rx;
        float v = 0.f;
        if ((unsigned)gy < 256u && (unsigned)gx < 256u)
            v = img[(ci * 256 + gy) * 256 + gx];
        s_in[ci][ry][rx & 1][rx >> 1] = v;
    }
    __syncthreads();

    int ti = t >> 4, tj = t & 15;
    float acc[CO];
#pragma unroll
    for (int c = 0; c < CO; ++c) acc[c] = 0.f;

    const float* wp = wrep + h * (TAPS * CO);
    for (int ci = 0; ci < 3; ++ci)
        for (int ky = 0; ky < 7; ++ky) {
            const float* srow = &s_in[ci][2 * ti + ky][0][0];
            const float* wrow = wp + (ci * 7 + ky) * 7 * CO;
#pragma unroll
            for (int kx = 0; kx < 7; ++kx) {
                // local col = 2*tj + kx -> parity kx&1, index tj + (kx>>1)
                float iv = srow[(kx & 1) * 20 + tj + (kx >> 1)];
                const float* wk = wrow + kx * CO;
#pragma unroll
                for (int c = 0; c < CO; ++c)
                    acc[c] = fmaf(iv, wk[c], acc[c]);   // weight from SGPR
            }
        }

    int oi = i0 + ti, oj = j0 + tj;
    __hip_bfloat16* dst = (h == 0 ? A2 : B2)
                        + (size_t)(n * CO) * (OH * OW) + oi * OW + oj;
#pragma unroll
    for (int c = 0; c < CO; ++c) {
        float sc  = gamma[c] * rsqrtf(var[c] + BN_EPS);
        float val = acc[c] * sc;
        if (h == 1) val += beta[c] - mean[c] * sc;   // shift on B-half only
        dst[c * (OH * OW)] = __float2bfloat16(val);
    }
}

// ---------------------------------------------------------------------------
// K2: pool. Grid = 64 channels x 8 row-tiles. Block stages the 17-row slices
// of ALL 8 nodes for both tensors (bf16, 74 KB LDS) -> A2/B2 read from global
// exactly once. Then loops all 64 edges from LDS: z = relu(a2+b2) fused into
// maxpool 3x3 s2 (run-of-8 outputs per lane), partial row-tile sums out.
#define POOL_RS 136   // LDS row stride in elems (272 B = 17 x 16 B)

__global__ __launch_bounds__(256, 2) void pool_kernel(
        const int* __restrict__ ei,
        const __hip_bfloat16* __restrict__ A2,
        const __hip_bfloat16* __restrict__ B2,
        float* __restrict__ partial) {
    int b  = blockIdx.x;     // 512 blocks
    int c  = b >> 3;         // channel
    int rt = b & 7;          // row-tile: output rows 8rt..8rt+7
    int t  = threadIdx.x;

    __shared__ __align__(16) unsigned short S[2][N_NODES][17][POOL_RS]; // 73,984 B

    // stage: 2 tensors x 8 nodes x 17 rows x 16 chunks of 16 B
    // global rows 16rt-1 .. 16rt+15 (row -1 zero-filled for rt==0)
    for (int k = t; k < 2 * N_NODES * 17 * 16; k += 256) {
        int w   = k & 15;
        int r17 = (k >> 4) % 17;
        int tn  = (k >> 4) / 17;          // tensor*8 + node
        int tensor = tn >> 3, node = tn & 7;
        int grow = 16 * rt - 1 + r17;
        uint4 v = make_uint4(0u, 0u, 0u, 0u);
        if (grow >= 0) {
            const unsigned short* bp = tensor ? (const unsigned short*)B2
                                              : (const unsigned short*)A2;
            v = *((const uint4*)(bp + (size_t)(node * CO + c) * (OH * OW)
                                    + grow * OW) + w);
        }
        *(uint4*)&S[tensor][node][r17][w * 8] = v;
    }
    __syncthreads();

    int lane = t & 63;
    int wv   = t >> 6;
    int p    = lane >> 3;    // local output row 0..7
    int tc   = lane & 7;     // col-run: outputs 8tc..8tc+7

    for (int i = 0; i < 16; ++i) {
        int e = wv + 4 * i;                 // wave-uniform edge
        int a0 = ei[e], a1 = ei[N_EDGES + e];
        int nmin = min(a0, a1), nmax = max(a0, a1);
        const unsigned short* ra = &S[0][nmin][2 * p][0];
        const unsigned short* rb = &S[1][nmax][2 * p][0];

        float vm[17];                       // vertical max of (a+b), cols 16tc-1..16tc+15
#pragma unroll
        for (int k = 0; k < 17; ++k) vm[k] = 0.f;   // 0-init OK: relu clamps at 0

#pragma unroll
        for (int dy = 0; dy < 3; ++dy) {
            const unsigned short* qa = ra + dy * POOL_RS;
            const unsigned short* qb = rb + dy * POOL_RS;
            uint4 av0 = *(const uint4*)(qa + 16 * tc);
            uint4 av1 = *(const uint4*)(qa + 16 * tc + 8);
            uint4 bv0 = *(const uint4*)(qb + 16 * tc);
            uint4 bv1 = *(const uint4*)(qb + 16 * tc + 8);
            unsigned alv = tc ? *(const unsigned*)(qa + 16 * tc - 2) : 0u;
            unsigned blv = tc ? *(const unsigned*)(qb + 16 * tc - 2) : 0u;
            vm[0] = fmaxf(vm[0], bhi(alv) + bhi(blv));
            unsigned aw[8] = {av0.x, av0.y, av0.z, av0.w, av1.x, av1.y, av1.z, av1.w};
            unsigned bw[8] = {bv0.x, bv0.y, bv0.z, bv0.w, bv1.x, bv1.y, bv1.z, bv1.w};
#pragma unroll
            for (int w2 = 0; w2 < 8; ++w2) {
                vm[1 + 2 * w2] = fmaxf(vm[1 + 2 * w2], blo(aw[w2]) + blo(bw[w2]));
                vm[2 + 2 * w2] = fmaxf(vm[2 + 2 * w2], bhi(aw[w2]) + bhi(bw[w2]));
            }
        }

        float ts = 0.f;
#pragma unroll
        for (int q = 0; q < 8; ++q)         // out col q: window = vm[2q..2q+2]
            ts += fmaxf(fmaxf(vm[2 * q], vm[2 * q + 1]), fmaxf(vm[2 * q + 2], 0.f));

#pragma unroll
        for (int off = 32; off > 0; off >>= 1)
            ts += __shfl_down(ts, off, 64);
        if (lane == 0)
            partial[rt * (N_EDGES * CO) + e * CO + c] = ts;
    }
}

// ---------------------------------------------------------------------------
// K3: pl = mean = sum(partial)/4096; ef = relu(pl @ fc_w^T + b); two heads
// fused as 6 running dots + block reduce.
__global__ __launch_bounds__(256) void head_kernel(
        const float* __restrict__ partial,
        const float* __restrict__ fc_w,   const float* __restrict__ fc_b,
        const float* __restrict__ xyz_w,  const float* __restrict__ xyz_b,
        const float* __restrict__ wpqr_w, const float* __restrict__ wpqr_b,
        float* __restrict__ out) {
    int e = blockIdx.x;
    int t = threadIdx.x;
    __shared__ float pl[CO];
    if (t < CO) {
        float s = 0.f;
#pragma unroll
        for (int rt = 0; rt < 8; ++rt)
            s += partial[rt * (N_EDGES * CO) + e * CO + t];
        pl[t] = s * (1.f / 4096.f);
    }
    __syncthreads();

    float s[6] = {0.f, 0.f, 0.f, 0.f, 0.f, 0.f};
#pragma unroll
    for (int ff = 0; ff < 4; ++ff) {
        int f = ff * 256 + t;
        const float* wr = fc_w + f * CO;
        float d = fc_b[f];
#pragma unroll
        for (int c = 0; c < CO; ++c) d = fmaf(pl[c], wr[c], d);
        d = fmaxf(d, 0.f);
#pragma unroll
        for (int r = 0; r < 3; ++r) {
            s[r]     = fmaf(d, xyz_w[r * FEAT + f],  s[r]);
            s[3 + r] = fmaf(d, wpqr_w[r * FEAT + f], s[3 + r]);
        }
    }
#pragma unroll
    for (int r = 0; r < 6; ++r)
#pragma unroll
        for (int off = 32; off > 0; off >>= 1)
            s[r] += __shfl_down(s[r], off, 64);

    __shared__ float red[4][6];
    if ((t & 63) == 0) {
#pragma unroll
        for (int r = 0; r < 6; ++r) red[t >> 6][r] = s[r];
    }
    __syncthreads();
    if (t < 6) {
        float v = red[0][t] + red[1][t] + red[2][t] + red[3][t];
        v += (t < 3) ? xyz_b[t] : wpqr_b[t - 3];
        out[48 + e * 6 + t] = v;         // full (output 1)
        if (e < 8) out[e * 6 + t] = v;   // full[:8] (output 0)
    }
}

// ---------------------------------------------------------------------------
extern "C" void kernel_launch(void* const* d_in, const int* in_sizes, int n_in,
                              void* d_out, int out_size, void* d_ws, size_t ws_size,
                              hipStream_t stream) {
    const float* x        = (const float*)d_in[0];
    const int*   ei       = (const int*)d_in[1];
    const float* conv1_w  = (const float*)d_in[2];
    const float* bn_gamma = (const float*)d_in[3];
    const float* bn_beta  = (const float*)d_in[4];
    const float* bn_mean  = (const float*)d_in[5];
    const float* bn_var   = (const float*)d_in[6];
    const float* fc_w     = (const float*)d_in[7];
    const float* fc_b     = (const float*)d_in[8];
    const float* xyz_w    = (const float*)d_in[9];
    const float* xyz_b    = (const float*)d_in[10];
    const float* wpqr_w   = (const float*)d_in[11];
    const float* wpqr_b   = (const float*)d_in[12];
    float* out = (float*)d_out;

    char* ws = (char*)d_ws;
    float*          wrep    = (float*)(ws + OFF_WREP);
    float*          partial = (float*)(ws + OFF_PARTIAL);  // aliases wrep (dead after conv)
    __hip_bfloat16* A2      = (__hip_bfloat16*)(ws + OFF_A);
    __hip_bfloat16* B2      = (__hip_bfloat16*)(ws + OFF_B);

    repack_kernel<<<(2 * TAPS * CO + 255) / 256, 256, 0, stream>>>(conv1_w, wrep);
    conv_kernel<<<1024, 256, 0, stream>>>(x, wrep, bn_gamma, bn_beta, bn_mean,
                                          bn_var, A2, B2);
    pool_kernel<<<512, 256, 0, stream>>>(ei, A2, B2, partial);
    head_kernel<<<64, 256, 0, stream>>>(partial, fc_w, fc_b,
                                        xyz_w, xyz_b, wpqr_w, wpqr_b, out);
}

// Round 3
// 152.542 us; speedup vs baseline: 1.3687x; 1.1673x over previous
//
#include <hip/hip_runtime.h>
#include <hip/hip_bf16.h>

// Problem constants
#define N_NODES 8
#define N_EDGES 64
#define CO 64
#define OH 128
#define OW 128
#define FEAT 1024
#define BN_EPS 1e-5f

// Workspace layout (bytes) — keep total under the proven ~33.7 MB bound:
//   pooled @ 0       : 64*64 fp32 = 16,384           (zeroed by repack, atomicAdd by pool)
//   wb     @ 16384   : 2*64*192 bf16 = 49,152        (BN-scaled, tap-remapped weights)
//   shiftb @ 65536   : 64 fp32 = 256
//   A2     @ 65792   : 8*64*128*128 bf16 = 16,777,216
//   B2     @ 16843008: 16,777,216                    (ends 33,620,224)
#define OFF_POOLED 0
#define OFF_WB     16384
#define OFF_SHIFT  65536
#define OFF_A      65792
#define OFF_B      (65792 + 16777216)

typedef short bf16x8 __attribute__((ext_vector_type(8)));
typedef float f32x4  __attribute__((ext_vector_type(4)));

__device__ __forceinline__ unsigned short f2bf(float f) {   // RNE f32->bf16
    unsigned u = __float_as_uint(f);
    u += 0x7fffu + ((u >> 16) & 1u);
    return (unsigned short)(u >> 16);
}
__device__ __forceinline__ float blo(unsigned u) { return __uint_as_float(u << 16); }
__device__ __forceinline__ float bhi(unsigned u) { return __uint_as_float(u & 0xffff0000u); }

// ---------------------------------------------------------------------------
// K0: weight repack + BN-scale fold + pooled zero.
// Tap space: t = (ci*7+ky)*8 + kx, kx in [0,8) (kx==7 is zero), rr=t>>3 in
// [0,24) with rr>=21 zero. K padded to 192 (6 MFMA K-steps of 32).
// wb[h][c][t] bf16 = w[c][h*3+ci][ky][kx] * (gamma_c * rsqrt(var_c+eps)).
__global__ __launch_bounds__(256) void repack_kernel(
        const float* __restrict__ w,
        const float* __restrict__ gamma, const float* __restrict__ beta,
        const float* __restrict__ mean,  const float* __restrict__ var,
        unsigned short* __restrict__ wb, float* __restrict__ shiftb,
        float* __restrict__ pooled) {
    int idx = blockIdx.x * 256 + threadIdx.x;
    if (idx < 2 * 64 * 192) {
        int t = idx % 192;
        int c = (idx / 192) & 63;
        int h = idx / (192 * 64);
        int rr = t >> 3, kx = t & 7;
        float val = 0.f;
        if (rr < 21 && kx < 7) {
            int ci = rr / 7, ky = rr % 7;
            float sc = gamma[c] * rsqrtf(var[c] + BN_EPS);
            val = w[((c * 6 + h * 3 + ci) * 7 + ky) * 7 + kx] * sc;
        }
        wb[idx] = f2bf(val);
    }
    if (idx < 64) {
        float sc = gamma[idx] * rsqrtf(var[idx] + BN_EPS);
        shiftb[idx] = beta[idx] - mean[idx] * sc;
    }
    if (idx < 64 * 64) pooled[idx] = 0.f;
}

// ---------------------------------------------------------------------------
// K1: MFMA conv. Grid 1024 = 8 nodes x 128 output rows; 256 thr = 4 waves.
// Block computes C[128ch(2 halves x 64)][128px] for one (n, oy).
// Wave w: px 32w..32w+31 (2 N-tiles), all 8 M-tiles (h=mt>>2, ch=16*(mt&3)+m).
// B-fragments: 8 consecutive bf16 from raw row rr=4s+q at col 2*ox -> 4 LDS
// u32 reads, conflict-free (row stride 136 words = 8 mod 32 tiles the q-windows).
// A-fragments: global dwordx4 from wb (L2-resident).
#define RS_W 136   // raw row stride in u32 words (272 bf16 elems; 262 used)

__global__ __launch_bounds__(256, 4) void conv_kernel(
        const float* __restrict__ x, const unsigned short* __restrict__ wb,
        const float* __restrict__ shiftb,
        unsigned short* __restrict__ A2, unsigned short* __restrict__ B2) {
    int n  = blockIdx.x >> 7;
    int oy = blockIdx.x & 127;
    int t  = threadIdx.x;

    __shared__ unsigned rawu[24 * RS_W];   // 13,056 B

    // stage: rows rr=(ci,ky) as bf16 pairs; cols rc=2u,2u+1 <-> img col rc-3
    const float* img = x + (size_t)n * (3 * 256 * 256);
    for (int k = t; k < 24 * RS_W; k += 256) {
        int u  = k % RS_W;
        int rr = k / RS_W;
        unsigned val = 0u;
        if (rr < 21 && u < 131) {
            int ci = rr / 7, ky = rr % 7;
            int iy = 2 * oy - 3 + ky;
            if ((unsigned)iy < 256u) {
                int c0 = 2 * u - 3;
                const float* row = img + (ci * 256 + iy) * 256;
                float f0 = ((unsigned)c0 < 256u) ? row[c0] : 0.f;
                float f1 = ((unsigned)(c0 + 1) < 256u) ? row[c0 + 1] : 0.f;
                val = (unsigned)f2bf(f0) | ((unsigned)f2bf(f1) << 16);
            }
        }
        rawu[k] = val;
    }
    __syncthreads();

    int wv = t >> 6, lane = t & 63;
    int quad = lane >> 4, m = lane & 15;

    f32x4 acc[8][2];
#pragma unroll
    for (int a = 0; a < 8; ++a) {
        acc[a][0] = (f32x4){0.f, 0.f, 0.f, 0.f};
        acc[a][1] = (f32x4){0.f, 0.f, 0.f, 0.f};
    }

    const bf16x8* wv8 = (const bf16x8*)wb;   // index: (h*64+c)*24 + 4s + q

#pragma unroll
    for (int s = 0; s < 6; ++s) {
        bf16x8 bfrag[2];
#pragma unroll
        for (int nt = 0; nt < 2; ++nt) {
            int ox = 32 * wv + 16 * nt + m;          // B lane col n = lane&15
            int base = (4 * s + quad) * RS_W + ox;   // words ox..ox+3 = cols 2ox..2ox+7
            union { unsigned u[4]; bf16x8 v; } bb;
            bb.u[0] = rawu[base];     bb.u[1] = rawu[base + 1];
            bb.u[2] = rawu[base + 2]; bb.u[3] = rawu[base + 3];
            bfrag[nt] = bb.v;
        }
#pragma unroll
        for (int mt = 0; mt < 8; ++mt) {
            int h = mt >> 2;
            int c = 16 * (mt & 3) + m;               // A lane row m = lane&15
            bf16x8 afrag = wv8[(h * 64 + c) * 24 + 4 * s + quad];
            acc[mt][0] = __builtin_amdgcn_mfma_f32_16x16x32_bf16(
                             afrag, bfrag[0], acc[mt][0], 0, 0, 0);
            acc[mt][1] = __builtin_amdgcn_mfma_f32_16x16x32_bf16(
                             afrag, bfrag[1], acc[mt][1], 0, 0, 0);
        }
    }

    // epilogue: D row = quad*4+r (ch within 16-tile), col = lane&15 (px)
#pragma unroll
    for (int mt = 0; mt < 8; ++mt) {
        int h = mt >> 2;
        unsigned short* dst = h ? B2 : A2;
#pragma unroll
        for (int nt = 0; nt < 2; ++nt) {
            int px = 32 * wv + 16 * nt + m;
#pragma unroll
            for (int r = 0; r < 4; ++r) {
                int ch = 16 * (mt & 3) + 4 * quad + r;
                float v = acc[mt][nt][r];
                if (h) v += shiftb[ch];
                dst[((size_t)(n * CO + ch) << 14) + (oy << 7) + px] = f2bf(v);
            }
        }
    }
}

// ---------------------------------------------------------------------------
// K2: pool. Grid 1024 = 64 ch x 16 row-tiles (4 out rows each); 256 thr.
// Stage 9 input rows x 128 cols for all 8 nodes x 2 tensors (36.9 KB LDS,
// 4 blocks/CU). Lane = (esub 0..3, tc 0..15): 4 edges per wave-iter, lane
// owns out rows 4rt..4rt+3 x out cols 4tc..4tc+3, streams the 9 rows once.
// All b128 reads hit the 8-way b128 floor (plane/row strides = 0 mod 32 words).
__global__ __launch_bounds__(256) void pool_kernel(
        const int* __restrict__ ei,
        const unsigned short* __restrict__ A2,
        const unsigned short* __restrict__ B2,
        float* __restrict__ pooled) {
    int b  = blockIdx.x;
    int c  = b >> 4;
    int rt = b & 15;
    int t  = threadIdx.x;

    __shared__ unsigned short S[2 * 8 * 9 * 128];   // plane 1152, row 128

    for (int k = t; k < 2304; k += 256) {           // 9 uint4 per thread
        int slot = k & 15;
        int r    = (k >> 4) % 9;
        int tn   = (k >> 4) / 9;                    // tensor*8 + node
        int grow = 8 * rt - 1 + r;
        uint4 v = make_uint4(0u, 0u, 0u, 0u);
        if (grow >= 0) {
            const unsigned short* src = (tn >= 8) ? B2 : A2;
            int node = tn & 7;
            v = *(const uint4*)(src + ((size_t)(node * CO + c) << 14)
                                    + (grow << 7) + slot * 8);
        }
        *(uint4*)&S[tn * 1152 + (r << 7) + slot * 8] = v;
    }
    __syncthreads();

    int wv = t >> 6, lane = t & 63;
    int esub = lane >> 4, tc = lane & 15;

    for (int i = 0; i < 4; ++i) {
        int e = 16 * wv + 4 * i + esub;             // per-lane edge
        int a0 = ei[e], a1 = ei[N_EDGES + e];
        int nmin = min(a0, a1), nmax = max(a0, a1);
        const unsigned short* pa = &S[nmin * 1152];
        const unsigned short* pb = &S[(8 + nmax) * 1152];

        float mx[4][4];
#pragma unroll
        for (int p = 0; p < 4; ++p)
#pragma unroll
            for (int q = 0; q < 4; ++q) mx[p][q] = 0.f;  // final clamp>=0 anyway

#pragma unroll
        for (int r = 0; r < 9; ++r) {
            uint4 ga = *(const uint4*)(pa + (r << 7) + tc * 8);
            uint4 gb = *(const uint4*)(pb + (r << 7) + tc * 8);
            float ha = 0.f, hb = 0.f;
            if (tc > 0) {                           // col 8tc-1 (hi of prev u32)
                ha = bhi(*(const unsigned*)(pa + (r << 7) + tc * 8 - 2));
                hb = bhi(*(const unsigned*)(pb + (r << 7) + tc * 8 - 2));
            }
            float z0 = ha + hb;
            float z1 = blo(ga.x) + blo(gb.x), z2 = bhi(ga.x) + bhi(gb.x);
            float z3 = blo(ga.y) + blo(gb.y), z4 = bhi(ga.y) + bhi(gb.y);
            float z5 = blo(ga.z) + blo(gb.z), z6 = bhi(ga.z) + bhi(gb.z);
            float z7 = blo(ga.w) + blo(gb.w), z8 = bhi(ga.w) + bhi(gb.w);
            float h0 = fmaxf(fmaxf(z0, z1), z2);
            float h1 = fmaxf(fmaxf(z2, z3), z4);
            float h2 = fmaxf(fmaxf(z4, z5), z6);
            float h3 = fmaxf(fmaxf(z6, z7), z8);
            // input row r (global 8rt-1+r): r odd -> out row (r-1)/2;
            // r even -> out rows r/2-1 and r/2 (clamped to [0,3])
            if (r & 1) {
                int p = (r - 1) >> 1;
                mx[p][0] = fmaxf(mx[p][0], h0); mx[p][1] = fmaxf(mx[p][1], h1);
                mx[p][2] = fmaxf(mx[p][2], h2); mx[p][3] = fmaxf(mx[p][3], h3);
            } else {
                if (r >= 2) {
                    int p = (r >> 1) - 1;
                    mx[p][0] = fmaxf(mx[p][0], h0); mx[p][1] = fmaxf(mx[p][1], h1);
                    mx[p][2] = fmaxf(mx[p][2], h2); mx[p][3] = fmaxf(mx[p][3], h3);
                }
                if (r <= 6) {
                    int p = r >> 1;
                    mx[p][0] = fmaxf(mx[p][0], h0); mx[p][1] = fmaxf(mx[p][1], h1);
                    mx[p][2] = fmaxf(mx[p][2], h2); mx[p][3] = fmaxf(mx[p][3], h3);
                }
            }
        }

        float sum = 0.f;
#pragma unroll
        for (int p = 0; p < 4; ++p)
#pragma unroll
            for (int q = 0; q < 4; ++q) sum += fmaxf(mx[p][q], 0.f);

        sum += __shfl_down(sum, 8, 64);
        sum += __shfl_down(sum, 4, 64);
        sum += __shfl_down(sum, 2, 64);
        sum += __shfl_down(sum, 1, 64);
        if (tc == 0) atomicAdd(&pooled[(e << 6) + c], sum);
    }
}

// ---------------------------------------------------------------------------
// K3: pl = pooled/4096; ef = relu(pl @ fc_w^T + b); heads fused (6 dots).
__global__ __launch_bounds__(256) void head_kernel(
        const float* __restrict__ pooled,
        const float* __restrict__ fc_w,   const float* __restrict__ fc_b,
        const float* __restrict__ xyz_w,  const float* __restrict__ xyz_b,
        const float* __restrict__ wpqr_w, const float* __restrict__ wpqr_b,
        float* __restrict__ out) {
    int e = blockIdx.x;
    int t = threadIdx.x;
    __shared__ float pl[CO];
    if (t < CO) pl[t] = pooled[(e << 6) + t] * (1.f / 4096.f);
    __syncthreads();

    float s[6] = {0.f, 0.f, 0.f, 0.f, 0.f, 0.f};
#pragma unroll
    for (int ff = 0; ff < 4; ++ff) {
        int f = ff * 256 + t;
        const float* wr = fc_w + f * CO;
        float d = fc_b[f];
#pragma unroll
        for (int c = 0; c < CO; ++c) d = fmaf(pl[c], wr[c], d);
        d = fmaxf(d, 0.f);
#pragma unroll
        for (int r = 0; r < 3; ++r) {
            s[r]     = fmaf(d, xyz_w[r * FEAT + f],  s[r]);
            s[3 + r] = fmaf(d, wpqr_w[r * FEAT + f], s[3 + r]);
        }
    }
#pragma unroll
    for (int r = 0; r < 6; ++r)
#pragma unroll
        for (int off = 32; off > 0; off >>= 1)
            s[r] += __shfl_down(s[r], off, 64);

    __shared__ float red[4][6];
    if ((t & 63) == 0) {
#pragma unroll
        for (int r = 0; r < 6; ++r) red[t >> 6][r] = s[r];
    }
    __syncthreads();
    if (t < 6) {
        float v = red[0][t] + red[1][t] + red[2][t] + red[3][t];
        v += (t < 3) ? xyz_b[t] : wpqr_b[t - 3];
        out[48 + e * 6 + t] = v;
        if (e < 8) out[e * 6 + t] = v;
    }
}

// ---------------------------------------------------------------------------
extern "C" void kernel_launch(void* const* d_in, const int* in_sizes, int n_in,
                              void* d_out, int out_size, void* d_ws, size_t ws_size,
                              hipStream_t stream) {
    const float* x        = (const float*)d_in[0];
    const int*   ei       = (const int*)d_in[1];
    const float* conv1_w  = (const float*)d_in[2];
    const float* bn_gamma = (const float*)d_in[3];
    const float* bn_beta  = (const float*)d_in[4];
    const float* bn_mean  = (const float*)d_in[5];
    const float* bn_var   = (const float*)d_in[6];
    const float* fc_w     = (const float*)d_in[7];
    const float* fc_b     = (const float*)d_in[8];
    const float* xyz_w    = (const float*)d_in[9];
    const float* xyz_b    = (const float*)d_in[10];
    const float* wpqr_w   = (const float*)d_in[11];
    const float* wpqr_b   = (const float*)d_in[12];
    float* out = (float*)d_out;

    char* ws = (char*)d_ws;
    float*          pooled = (float*)(ws + OFF_POOLED);
    unsigned short* wb     = (unsigned short*)(ws + OFF_WB);
    float*          shiftb = (float*)(ws + OFF_SHIFT);
    unsigned short* A2     = (unsigned short*)(ws + OFF_A);
    unsigned short* B2     = (unsigned short*)(ws + OFF_B);

    repack_kernel<<<96, 256, 0, stream>>>(conv1_w, bn_gamma, bn_beta, bn_mean,
                                          bn_var, wb, shiftb, pooled);
    conv_kernel<<<1024, 256, 0, stream>>>(x, wb, shiftb, A2, B2);
    pool_kernel<<<1024, 256, 0, stream>>>(ei, A2, B2, pooled);
    head_kernel<<<64, 256, 0, stream>>>(pooled, fc_w, fc_b,
                                        xyz_w, xyz_b, wpqr_w, wpqr_b, out);
}

// Round 4
// 145.620 us; speedup vs baseline: 1.4337x; 1.0475x over previous
//
#include <hip/hip_runtime.h>
#include <hip/hip_bf16.h>

// Problem constants
#define N_NODES 8
#define N_EDGES 64
#define CO 64
#define OH 128
#define OW 128
#define FEAT 1024
#define BN_EPS 1e-5f

// Workspace layout (bytes):
//   pooled @ 0       : 64*64 fp32 = 16,384           (zeroed by repack, atomicAdd by pool)
//   wb2    @ 16384   : 24*128*8 bf16 = 49,152        (weights, [rr][h*64+c][kx] layout)
//   shiftb @ 65536   : 64 fp32 = 256
//   A2     @ 65792   : 8*64*128*128 bf16 = 16,777,216
//   B2     @ 16843008: 16,777,216                    (ends 33,620,224)
#define OFF_POOLED 0
#define OFF_WB     16384
#define OFF_SHIFT  65536
#define OFF_A      65792
#define OFF_B      (65792 + 16777216)

typedef short bf16x8 __attribute__((ext_vector_type(8)));
typedef float f32x4  __attribute__((ext_vector_type(4)));

__device__ __forceinline__ unsigned short f2bf(float f) {   // RNE f32->bf16
    unsigned u = __float_as_uint(f);
    u += 0x7fffu + ((u >> 16) & 1u);
    return (unsigned short)(u >> 16);
}
__device__ __forceinline__ float blo(unsigned u) { return __uint_as_float(u << 16); }
__device__ __forceinline__ float bhi(unsigned u) { return __uint_as_float(u & 0xffff0000u); }

// ---------------------------------------------------------------------------
// K0: weight repack + BN-scale fold + pooled zero.
// Tap space: t = (ci*7+ky)*8 + kx, kx in [0,8) (kx==7 zero), rr = t>>3 in
// [0,24) (rr>=21 zero). NEW layout: wb2[(rr*128 + h*64 + c)*8 + kx] so conv
// can stage it to LDS with a straight coalesced copy.
__global__ __launch_bounds__(256) void repack_kernel(
        const float* __restrict__ w,
        const float* __restrict__ gamma, const float* __restrict__ beta,
        const float* __restrict__ mean,  const float* __restrict__ var,
        unsigned short* __restrict__ wb2, float* __restrict__ shiftb,
        float* __restrict__ pooled) {
    int idx = blockIdx.x * 256 + threadIdx.x;
    if (idx < 2 * 64 * 192) {
        int t = idx % 192;
        int c = (idx / 192) & 63;
        int h = idx / (192 * 64);
        int rr = t >> 3, kx = t & 7;
        float val = 0.f;
        if (rr < 21 && kx < 7) {
            int ci = rr / 7, ky = rr % 7;
            float sc = gamma[c] * rsqrtf(var[c] + BN_EPS);
            val = w[((c * 6 + h * 3 + ci) * 7 + ky) * 7 + kx] * sc;
        }
        wb2[(rr * 128 + h * 64 + c) * 8 + kx] = f2bf(val);
    }
    if (idx < 64) {
        float sc = gamma[idx] * rsqrtf(var[idx] + BN_EPS);
        shiftb[idx] = beta[idx] - mean[idx] * sc;
    }
    if (idx < 64 * 64) pooled[idx] = 0.f;
}

// ---------------------------------------------------------------------------
// K1: MFMA conv, swapped operands: D = mfma(img_frag, w_frag) so D rows = px.
// Grid 1024 = 8 nodes x 128 oy; 512 thr = 8 waves: wave wv -> h = wv&1,
// px-group wg = wv>>1 (32 px). Per wave: 4 ch-tiles x 2 px-subtiles,
// acc[4][2] f32x4 = 32 VGPR. Weights read from LDS (b128, conflict-floor);
// image fragments from raw-row LDS (4x b32, 2-way = free).
// Epilogue: lane holds 4 consecutive px per (ct,nt) -> pack bf16 pairs,
// b64 LDS transpose, then coalesced uint4 global stores (256 B rows).
#define RS_W 136   // raw row stride in u32 words

__global__ __launch_bounds__(512, 4) void conv_kernel(
        const float* __restrict__ x, const unsigned short* __restrict__ wb2,
        const float* __restrict__ shiftb,
        unsigned short* __restrict__ A2, unsigned short* __restrict__ B2) {
    int n  = blockIdx.x >> 7;
    int oy = blockIdx.x & 127;
    int t  = threadIdx.x;

    // union: [rawu 13,056 B][wlds 49,152 B] = 62,208; epilogue T = 34,816 B
    __shared__ __align__(16) char smem[62208];
    unsigned* rawu = (unsigned*)smem;                 // [24][136] u32 (bf16 pairs)
    uint4*    wl4  = (uint4*)(smem + 13056);          // 3072 granules of bf16x8

    // stage weights: straight coalesced copy (layout prebuilt by repack)
    for (int k = t; k < 3072; k += 512)
        wl4[k] = ((const uint4*)wb2)[k];

    // stage image rows rr=(ci,ky): bf16 pairs, cols rc=2u,2u+1 <-> img col rc-3
    const float* img = x + (size_t)n * (3 * 256 * 256);
    for (int k = t; k < 24 * RS_W; k += 512) {
        int u  = k % RS_W;
        int rr = k / RS_W;
        unsigned val = 0u;
        if (rr < 21 && u < 131) {
            int ci = (rr * 147) >> 10;          // rr / 7 for rr < 24
            int ky = rr - ci * 7;
            int iy = 2 * oy - 3 + ky;
            if ((unsigned)iy < 256u) {
                int c0 = 2 * u - 3;
                const float* row = img + (ci * 256 + iy) * 256;
                float f0 = ((unsigned)c0 < 256u) ? row[c0] : 0.f;
                float f1 = ((unsigned)(c0 + 1) < 256u) ? row[c0 + 1] : 0.f;
                val = (unsigned)f2bf(f0) | ((unsigned)f2bf(f1) << 16);
            }
        }
        rawu[k] = val;
    }
    __syncthreads();

    int wv = t >> 6, lane = t & 63;
    int h  = wv & 1, wg = wv >> 1;        // half, px-group (32 px)
    int quad = lane >> 4, m = lane & 15;

    f32x4 acc[4][2];
#pragma unroll
    for (int ct = 0; ct < 4; ++ct) {
        acc[ct][0] = (f32x4){0.f, 0.f, 0.f, 0.f};
        acc[ct][1] = (f32x4){0.f, 0.f, 0.f, 0.f};
    }

    const bf16x8* wlv = (const bf16x8*)(smem + 13056);

#pragma unroll
    for (int s = 0; s < 6; ++s) {
        int rq = 4 * s + quad;
        bf16x8 afrag[2];                   // image: A[m=px][k]
#pragma unroll
        for (int nt = 0; nt < 2; ++nt) {
            int ox = 32 * wg + 16 * nt + m;
            int base = rq * RS_W + ox;     // words ox..ox+3 = cols 2ox..2ox+7
            union { unsigned u[4]; bf16x8 v; } bb;
            bb.u[0] = rawu[base];     bb.u[1] = rawu[base + 1];
            bb.u[2] = rawu[base + 2]; bb.u[3] = rawu[base + 3];
            afrag[nt] = bb.v;
        }
#pragma unroll
        for (int ct = 0; ct < 4; ++ct) {
            bf16x8 wfrag = wlv[rq * 128 + h * 64 + 16 * ct + m];  // B[k][n=ch]
#pragma unroll
            for (int nt = 0; nt < 2; ++nt)
                acc[ct][nt] = __builtin_amdgcn_mfma_f32_16x16x32_bf16(
                                  afrag[nt], wfrag, acc[ct][nt], 0, 0, 0);
        }
    }

    // shift for B-half (before bf16 conversion)
    float sh[4] = {0.f, 0.f, 0.f, 0.f};
    if (h) {
#pragma unroll
        for (int ct = 0; ct < 4; ++ct) sh[ct] = shiftb[16 * ct + m];
    }

    __syncthreads();                       // smem reuse as transpose buffer
    unsigned short* T = (unsigned short*)smem;   // [128 ch'][136 px-padded]

#pragma unroll
    for (int ct = 0; ct < 4; ++ct) {
        int chp = h * 64 + 16 * ct + m;    // row in T
#pragma unroll
        for (int nt = 0; nt < 2; ++nt) {
            int px0 = 32 * wg + 16 * nt + 4 * quad;
            float v0 = acc[ct][nt][0] + sh[ct];
            float v1 = acc[ct][nt][1] + sh[ct];
            float v2 = acc[ct][nt][2] + sh[ct];
            float v3 = acc[ct][nt][3] + sh[ct];
            uint2 pk;
            pk.x = (unsigned)f2bf(v0) | ((unsigned)f2bf(v1) << 16);
            pk.y = (unsigned)f2bf(v2) | ((unsigned)f2bf(v3) << 16);
            *(uint2*)&T[chp * 136 + px0] = pk;   // b64, near bank-floor
        }
    }
    __syncthreads();

    // cooperative coalesced store: thread -> (ch-row, 32-px slot), 4x uint4
    int row = t >> 2, slot = t & 3;        // row = h*64 + ch
    int hh = row >> 6, ch = row & 63;
    unsigned short* dst = (hh ? B2 : A2)
                        + ((size_t)(n * CO + ch) << 14) + (oy << 7) + slot * 32;
#pragma unroll
    for (int i = 0; i < 4; ++i)
        *(uint4*)(dst + i * 8) = *(uint4*)&T[row * 136 + slot * 32 + i * 8];
}

// ---------------------------------------------------------------------------
// K2: pool (unchanged from R3). Grid 1024 = 64 ch x 16 row-tiles; 256 thr.
__global__ __launch_bounds__(256) void pool_kernel(
        const int* __restrict__ ei,
        const unsigned short* __restrict__ A2,
        const unsigned short* __restrict__ B2,
        float* __restrict__ pooled) {
    int b  = blockIdx.x;
    int c  = b >> 4;
    int rt = b & 15;
    int t  = threadIdx.x;

    __shared__ unsigned short S[2 * 8 * 9 * 128];   // plane 1152, row 128

    for (int k = t; k < 2304; k += 256) {
        int slot = k & 15;
        int r    = (k >> 4) % 9;
        int tn   = (k >> 4) / 9;
        int grow = 8 * rt - 1 + r;
        uint4 v = make_uint4(0u, 0u, 0u, 0u);
        if (grow >= 0) {
            const unsigned short* src = (tn >= 8) ? B2 : A2;
            int node = tn & 7;
            v = *(const uint4*)(src + ((size_t)(node * CO + c) << 14)
                                    + (grow << 7) + slot * 8);
        }
        *(uint4*)&S[tn * 1152 + (r << 7) + slot * 8] = v;
    }
    __syncthreads();

    int wv = t >> 6, lane = t & 63;
    int esub = lane >> 4, tc = lane & 15;

    for (int i = 0; i < 4; ++i) {
        int e = 16 * wv + 4 * i + esub;
        int a0 = ei[e], a1 = ei[N_EDGES + e];
        int nmin = min(a0, a1), nmax = max(a0, a1);
        const unsigned short* pa = &S[nmin * 1152];
        const unsigned short* pb = &S[(8 + nmax) * 1152];

        float mx[4][4];
#pragma unroll
        for (int p = 0; p < 4; ++p)
#pragma unroll
            for (int q = 0; q < 4; ++q) mx[p][q] = 0.f;

#pragma unroll
        for (int r = 0; r < 9; ++r) {
            uint4 ga = *(const uint4*)(pa + (r << 7) + tc * 8);
            uint4 gb = *(const uint4*)(pb + (r << 7) + tc * 8);
            float ha = 0.f, hb = 0.f;
            if (tc > 0) {
                ha = bhi(*(const unsigned*)(pa + (r << 7) + tc * 8 - 2));
                hb = bhi(*(const unsigned*)(pb + (r << 7) + tc * 8 - 2));
            }
            float z0 = ha + hb;
            float z1 = blo(ga.x) + blo(gb.x), z2 = bhi(ga.x) + bhi(gb.x);
            float z3 = blo(ga.y) + blo(gb.y), z4 = bhi(ga.y) + bhi(gb.y);
            float z5 = blo(ga.z) + blo(gb.z), z6 = bhi(ga.z) + bhi(gb.z);
            float z7 = blo(ga.w) + blo(gb.w), z8 = bhi(ga.w) + bhi(gb.w);
            float h0 = fmaxf(fmaxf(z0, z1), z2);
            float h1 = fmaxf(fmaxf(z2, z3), z4);
            float h2 = fmaxf(fmaxf(z4, z5), z6);
            float h3 = fmaxf(fmaxf(z6, z7), z8);
            if (r & 1) {
                int p = (r - 1) >> 1;
                mx[p][0] = fmaxf(mx[p][0], h0); mx[p][1] = fmaxf(mx[p][1], h1);
                mx[p][2] = fmaxf(mx[p][2], h2); mx[p][3] = fmaxf(mx[p][3], h3);
            } else {
                if (r >= 2) {
                    int p = (r >> 1) - 1;
                    mx[p][0] = fmaxf(mx[p][0], h0); mx[p][1] = fmaxf(mx[p][1], h1);
                    mx[p][2] = fmaxf(mx[p][2], h2); mx[p][3] = fmaxf(mx[p][3], h3);
                }
                if (r <= 6) {
                    int p = r >> 1;
                    mx[p][0] = fmaxf(mx[p][0], h0); mx[p][1] = fmaxf(mx[p][1], h1);
                    mx[p][2] = fmaxf(mx[p][2], h2); mx[p][3] = fmaxf(mx[p][3], h3);
                }
            }
        }

        float sum = 0.f;
#pragma unroll
        for (int p = 0; p < 4; ++p)
#pragma unroll
            for (int q = 0; q < 4; ++q) sum += fmaxf(mx[p][q], 0.f);

        sum += __shfl_down(sum, 8, 64);
        sum += __shfl_down(sum, 4, 64);
        sum += __shfl_down(sum, 2, 64);
        sum += __shfl_down(sum, 1, 64);
        if (tc == 0) atomicAdd(&pooled[(e << 6) + c], sum);
    }
}

// ---------------------------------------------------------------------------
// K3: head (unchanged).
__global__ __launch_bounds__(256) void head_kernel(
        const float* __restrict__ pooled,
        const float* __restrict__ fc_w,   const float* __restrict__ fc_b,
        const float* __restrict__ xyz_w,  const float* __restrict__ xyz_b,
        const float* __restrict__ wpqr_w, const float* __restrict__ wpqr_b,
        float* __restrict__ out) {
    int e = blockIdx.x;
    int t = threadIdx.x;
    __shared__ float pl[CO];
    if (t < CO) pl[t] = pooled[(e << 6) + t] * (1.f / 4096.f);
    __syncthreads();

    float s[6] = {0.f, 0.f, 0.f, 0.f, 0.f, 0.f};
#pragma unroll
    for (int ff = 0; ff < 4; ++ff) {
        int f = ff * 256 + t;
        const float* wr = fc_w + f * CO;
        float d = fc_b[f];
#pragma unroll
        for (int c = 0; c < CO; ++c) d = fmaf(pl[c], wr[c], d);
        d = fmaxf(d, 0.f);
#pragma unroll
        for (int r = 0; r < 3; ++r) {
            s[r]     = fmaf(d, xyz_w[r * FEAT + f],  s[r]);
            s[3 + r] = fmaf(d, wpqr_w[r * FEAT + f], s[3 + r]);
        }
    }
#pragma unroll
    for (int r = 0; r < 6; ++r)
#pragma unroll
        for (int off = 32; off > 0; off >>= 1)
            s[r] += __shfl_down(s[r], off, 64);

    __shared__ float red[4][6];
    if ((t & 63) == 0) {
#pragma unroll
        for (int r = 0; r < 6; ++r) red[t >> 6][r] = s[r];
    }
    __syncthreads();
    if (t < 6) {
        float v = red[0][t] + red[1][t] + red[2][t] + red[3][t];
        v += (t < 3) ? xyz_b[t] : wpqr_b[t - 3];
        out[48 + e * 6 + t] = v;
        if (e < 8) out[e * 6 + t] = v;
    }
}

// ---------------------------------------------------------------------------
extern "C" void kernel_launch(void* const* d_in, const int* in_sizes, int n_in,
                              void* d_out, int out_size, void* d_ws, size_t ws_size,
                              hipStream_t stream) {
    const float* x        = (const float*)d_in[0];
    const int*   ei       = (const int*)d_in[1];
    const float* conv1_w  = (const float*)d_in[2];
    const float* bn_gamma = (const float*)d_in[3];
    const float* bn_beta  = (const float*)d_in[4];
    const float* bn_mean  = (const float*)d_in[5];
    const float* bn_var   = (const float*)d_in[6];
    const float* fc_w     = (const float*)d_in[7];
    const float* fc_b     = (const float*)d_in[8];
    const float* xyz_w    = (const float*)d_in[9];
    const float* xyz_b    = (const float*)d_in[10];
    const float* wpqr_w   = (const float*)d_in[11];
    const float* wpqr_b   = (const float*)d_in[12];
    float* out = (float*)d_out;

    char* ws = (char*)d_ws;
    float*          pooled = (float*)(ws + OFF_POOLED);
    unsigned short* wb2    = (unsigned short*)(ws + OFF_WB);
    float*          shiftb = (float*)(ws + OFF_SHIFT);
    unsigned short* A2     = (unsigned short*)(ws + OFF_A);
    unsigned short* B2     = (unsigned short*)(ws + OFF_B);

    repack_kernel<<<96, 256, 0, stream>>>(conv1_w, bn_gamma, bn_beta, bn_mean,
                                          bn_var, wb2, shiftb, pooled);
    conv_kernel<<<1024, 512, 0, stream>>>(x, wb2, shiftb, A2, B2);
    pool_kernel<<<1024, 256, 0, stream>>>(ei, A2, B2, pooled);
    head_kernel<<<64, 256, 0, stream>>>(pooled, fc_w, fc_b,
                                        xyz_w, xyz_b, wpqr_w, wpqr_b, out);
}

// Round 5
// 137.806 us; speedup vs baseline: 1.5150x; 1.0567x over previous
//
#include <hip/hip_runtime.h>
#include <hip/hip_bf16.h>

// Problem constants
#define N_NODES 8
#define N_EDGES 64
#define CO 64
#define OH 128
#define OW 128
#define FEAT 1024
#define BN_EPS 1e-5f

// Workspace layout (bytes):
//   pooled @ 0       : 64*64 fp32 = 16,384   (indexed by pair code nmin*8+nmax;
//                                             zeroed by repack, atomicAdd by pool)
//   wb2    @ 16384   : 24*128*8 bf16 = 49,152  (weights, [rr][h*64+c][kx] layout)
//   shiftb @ 65536   : 64 fp32 = 256
//   A2     @ 65792   : 8*64*128*128 bf16 = 16,777,216
//   B2     @ 16843008: 16,777,216             (ends 33,620,224)
#define OFF_POOLED 0
#define OFF_WB     16384
#define OFF_SHIFT  65536
#define OFF_A      65792
#define OFF_B      (65792 + 16777216)

typedef short bf16x8 __attribute__((ext_vector_type(8)));
typedef float f32x4  __attribute__((ext_vector_type(4)));

__device__ __forceinline__ unsigned short f2bf(float f) {   // RNE f32->bf16
    unsigned u = __float_as_uint(f);
    u += 0x7fffu + ((u >> 16) & 1u);
    return (unsigned short)(u >> 16);
}
__device__ __forceinline__ float blo(unsigned u) { return __uint_as_float(u << 16); }
__device__ __forceinline__ float bhi(unsigned u) { return __uint_as_float(u & 0xffff0000u); }

// ---------------------------------------------------------------------------
// K0: weight repack + BN-scale fold + pooled zero.
// Tap space: t = (ci*7+ky)*8 + kx, kx in [0,8) (kx==7 zero), rr = t>>3 in
// [0,24) (rr>=21 zero). Layout: wb2[(rr*128 + h*64 + c)*8 + kx].
__global__ __launch_bounds__(256) void repack_kernel(
        const float* __restrict__ w,
        const float* __restrict__ gamma, const float* __restrict__ beta,
        const float* __restrict__ mean,  const float* __restrict__ var,
        unsigned short* __restrict__ wb2, float* __restrict__ shiftb,
        float* __restrict__ pooled) {
    int idx = blockIdx.x * 256 + threadIdx.x;
    if (idx < 2 * 64 * 192) {
        int t = idx % 192;
        int c = (idx / 192) & 63;
        int h = idx / (192 * 64);
        int rr = t >> 3, kx = t & 7;
        float val = 0.f;
        if (rr < 21 && kx < 7) {
            int ci = rr / 7, ky = rr % 7;
            float sc = gamma[c] * rsqrtf(var[c] + BN_EPS);
            val = w[((c * 6 + h * 3 + ci) * 7 + ky) * 7 + kx] * sc;
        }
        wb2[(rr * 128 + h * 64 + c) * 8 + kx] = f2bf(val);
    }
    if (idx < 64) {
        float sc = gamma[idx] * rsqrtf(var[idx] + BN_EPS);
        shiftb[idx] = beta[idx] - mean[idx] * sc;
    }
    if (idx < 64 * 64) pooled[idx] = 0.f;
}

// ---------------------------------------------------------------------------
// K1: MFMA conv, D = mfma(img_frag, w_frag). Grid 1024 = 8 nodes x 128 oy;
// 512 thr = 8 waves: h = wv&1, px-group wg = wv>>1.
// CHANGES vs R4: (a) weights NOT staged in LDS -- w-fragments are direct
// global bf16x8 loads from wb2 (48 KB, L1/L2-resident) -> LDS 62->35 KB;
// (b) K-loop `#pragma unroll 2` so live set (acc 32 + 2x24 frag VGPRs + addr)
// fits the 128-VGPR cap of (512,4) with NO scratch spill (R3/R4 full unroll
// wanted ~196 VGPRs -> spilled ~70/lane ~= 285 MB scratch traffic ~= 40 us).
#define RS_W 136   // raw row stride in u32 words

__global__ __launch_bounds__(512, 4) void conv_kernel(
        const float* __restrict__ x, const unsigned short* __restrict__ wb2,
        const float* __restrict__ shiftb,
        unsigned short* __restrict__ A2, unsigned short* __restrict__ B2) {
    int n  = blockIdx.x >> 7;
    int oy = blockIdx.x & 127;
    int t  = threadIdx.x;

    // union: rawu [24][136] u32 = 13,056 B; epilogue T [128][136] bf16 = 34,816 B
    __shared__ __align__(16) char smem[34816];
    unsigned* rawu = (unsigned*)smem;

    // stage image rows rr=(ci,ky): bf16 pairs, cols rc=2u,2u+1 <-> img col rc-3
    const float* img = x + (size_t)n * (3 * 256 * 256);
    for (int k = t; k < 24 * RS_W; k += 512) {
        int u  = k % RS_W;
        int rr = k / RS_W;
        unsigned val = 0u;
        if (rr < 21 && u < 131) {
            int ci = (rr * 147) >> 10;          // rr/7 for rr<24
            int ky = rr - ci * 7;
            int iy = 2 * oy - 3 + ky;
            if ((unsigned)iy < 256u) {
                int c0 = 2 * u - 3;
                const float* row = img + (ci * 256 + iy) * 256;
                float f0 = ((unsigned)c0 < 256u) ? row[c0] : 0.f;
                float f1 = ((unsigned)(c0 + 1) < 256u) ? row[c0 + 1] : 0.f;
                val = (unsigned)f2bf(f0) | ((unsigned)f2bf(f1) << 16);
            }
        }
        rawu[k] = val;
    }
    __syncthreads();

    int wv = t >> 6, lane = t & 63;
    int h  = wv & 1, wg = wv >> 1;
    int quad = lane >> 4, m = lane & 15;

    f32x4 acc[4][2];
#pragma unroll
    for (int ct = 0; ct < 4; ++ct) {
        acc[ct][0] = (f32x4){0.f, 0.f, 0.f, 0.f};
        acc[ct][1] = (f32x4){0.f, 0.f, 0.f, 0.f};
    }

    const bf16x8* wbv = (const bf16x8*)wb2;

#pragma unroll 2
    for (int s = 0; s < 6; ++s) {
        int rq = 4 * s + quad;
        bf16x8 afrag[2];                   // image: A[m=px][k]
#pragma unroll
        for (int nt = 0; nt < 2; ++nt) {
            int ox = 32 * wg + 16 * nt + m;
            int base = rq * RS_W + ox;
            union { unsigned u[4]; bf16x8 v; } bb;
            bb.u[0] = rawu[base];     bb.u[1] = rawu[base + 1];
            bb.u[2] = rawu[base + 2]; bb.u[3] = rawu[base + 3];
            afrag[nt] = bb.v;
        }
#pragma unroll
        for (int ct = 0; ct < 4; ++ct) {
            bf16x8 wfrag = wbv[rq * 128 + h * 64 + 16 * ct + m];  // global, L2-hot
#pragma unroll
            for (int nt = 0; nt < 2; ++nt)
                acc[ct][nt] = __builtin_amdgcn_mfma_f32_16x16x32_bf16(
                                  afrag[nt], wfrag, acc[ct][nt], 0, 0, 0);
        }
    }

    float sh[4] = {0.f, 0.f, 0.f, 0.f};
    if (h) {
#pragma unroll
        for (int ct = 0; ct < 4; ++ct) sh[ct] = shiftb[16 * ct + m];
    }

    __syncthreads();                       // smem reuse as transpose buffer
    unsigned short* T = (unsigned short*)smem;   // [128 ch'][136]

#pragma unroll
    for (int ct = 0; ct < 4; ++ct) {
        int chp = h * 64 + 16 * ct + m;
#pragma unroll
        for (int nt = 0; nt < 2; ++nt) {
            int px0 = 32 * wg + 16 * nt + 4 * quad;
            float v0 = acc[ct][nt][0] + sh[ct];
            float v1 = acc[ct][nt][1] + sh[ct];
            float v2 = acc[ct][nt][2] + sh[ct];
            float v3 = acc[ct][nt][3] + sh[ct];
            uint2 pk;
            pk.x = (unsigned)f2bf(v0) | ((unsigned)f2bf(v1) << 16);
            pk.y = (unsigned)f2bf(v2) | ((unsigned)f2bf(v3) << 16);
            *(uint2*)&T[chp * 136 + px0] = pk;
        }
    }
    __syncthreads();

    // cooperative coalesced store: thread -> (ch-row, 32-px slot), 4x uint4
    int row = t >> 2, slot = t & 3;
    int hh = row >> 6, ch = row & 63;
    unsigned short* dst = (hh ? B2 : A2)
                        + ((size_t)(n * CO + ch) << 14) + (oy << 7) + slot * 32;
#pragma unroll
    for (int i = 0; i < 4; ++i)
        *(uint4*)(dst + i * 8) = *(uint4*)&T[row * 136 + slot * 32 + i * 8];
}

// ---------------------------------------------------------------------------
// K2: pool over the 36 DISTINCT node pairs (pi<=pj), not 64 edges.
// Grid 1024 = 64 ch x 16 row-tiles; 256 thr; 3 pair-iters (48 slots >= 36).
// Result: atomicAdd into pooled[(pi*8+pj)*64 + c]; head gathers per edge.
__global__ __launch_bounds__(256, 4) void pool_kernel(
        const unsigned short* __restrict__ A2,
        const unsigned short* __restrict__ B2,
        float* __restrict__ pooled) {
    int b  = blockIdx.x;
    int c  = b >> 4;
    int rt = b & 15;
    int t  = threadIdx.x;

    __shared__ unsigned short S[2 * 8 * 9 * 128];   // plane 1152, row 128

    for (int k = t; k < 2304; k += 256) {
        int slot = k & 15;
        int r    = (k >> 4) % 9;
        int tn   = (k >> 4) / 9;
        int grow = 8 * rt - 1 + r;
        uint4 v = make_uint4(0u, 0u, 0u, 0u);
        if (grow >= 0) {
            const unsigned short* src = (tn >= 8) ? B2 : A2;
            int node = tn & 7;
            v = *(const uint4*)(src + ((size_t)(node * CO + c) << 14)
                                    + (grow << 7) + slot * 8);
        }
        *(uint4*)&S[tn * 1152 + (r << 7) + slot * 8] = v;
    }
    __syncthreads();

    int wv = t >> 6, lane = t & 63;
    int esub = lane >> 4, tc = lane & 15;

    for (int i = 0; i < 3; ++i) {
        int sidx = 12 * wv + 4 * i + esub;          // pair slot 0..47
        bool valid = sidx < 36;
        int ss = valid ? sidx : 0;
        int pi = 0, rem = ss;                        // unrank pair (pi<=pj)
        while (rem >= 8 - pi) { rem -= 8 - pi; ++pi; }
        int pj = pi + rem;
        const unsigned short* pa = &S[pi * 1152];
        const unsigned short* pb = &S[(8 + pj) * 1152];

        float mx[4][4];
#pragma unroll
        for (int p = 0; p < 4; ++p)
#pragma unroll
            for (int q = 0; q < 4; ++q) mx[p][q] = 0.f;

#pragma unroll
        for (int r = 0; r < 9; ++r) {
            uint4 ga = *(const uint4*)(pa + (r << 7) + tc * 8);
            uint4 gb = *(const uint4*)(pb + (r << 7) + tc * 8);
            float ha = 0.f, hb = 0.f;
            if (tc > 0) {
                ha = bhi(*(const unsigned*)(pa + (r << 7) + tc * 8 - 2));
                hb = bhi(*(const unsigned*)(pb + (r << 7) + tc * 8 - 2));
            }
            float z0 = ha + hb;
            float z1 = blo(ga.x) + blo(gb.x), z2 = bhi(ga.x) + bhi(gb.x);
            float z3 = blo(ga.y) + blo(gb.y), z4 = bhi(ga.y) + bhi(gb.y);
            float z5 = blo(ga.z) + blo(gb.z), z6 = bhi(ga.z) + bhi(gb.z);
            float z7 = blo(ga.w) + blo(gb.w), z8 = bhi(ga.w) + bhi(gb.w);
            float h0 = fmaxf(fmaxf(z0, z1), z2);
            float h1 = fmaxf(fmaxf(z2, z3), z4);
            float h2 = fmaxf(fmaxf(z4, z5), z6);
            float h3 = fmaxf(fmaxf(z6, z7), z8);
            if (r & 1) {
                int p = (r - 1) >> 1;
                mx[p][0] = fmaxf(mx[p][0], h0); mx[p][1] = fmaxf(mx[p][1], h1);
                mx[p][2] = fmaxf(mx[p][2], h2); mx[p][3] = fmaxf(mx[p][3], h3);
            } else {
                if (r >= 2) {
                    int p = (r >> 1) - 1;
                    mx[p][0] = fmaxf(mx[p][0], h0); mx[p][1] = fmaxf(mx[p][1], h1);
                    mx[p][2] = fmaxf(mx[p][2], h2); mx[p][3] = fmaxf(mx[p][3], h3);
                }
                if (r <= 6) {
                    int p = r >> 1;
                    mx[p][0] = fmaxf(mx[p][0], h0); mx[p][1] = fmaxf(mx[p][1], h1);
                    mx[p][2] = fmaxf(mx[p][2], h2); mx[p][3] = fmaxf(mx[p][3], h3);
                }
            }
        }

        float sum = 0.f;
#pragma unroll
        for (int p = 0; p < 4; ++p)
#pragma unroll
            for (int q = 0; q < 4; ++q) sum += fmaxf(mx[p][q], 0.f);

        sum += __shfl_down(sum, 8, 64);
        sum += __shfl_down(sum, 4, 64);
        sum += __shfl_down(sum, 2, 64);
        sum += __shfl_down(sum, 1, 64);
        if (tc == 0 && valid)
            atomicAdd(&pooled[((pi << 3) + pj) * 64 + c], sum);
    }
}

// ---------------------------------------------------------------------------
// K3: head — gather pooled by pair code, fc+relu+two heads fused.
__global__ __launch_bounds__(256) void head_kernel(
        const int* __restrict__ ei, const float* __restrict__ pooled,
        const float* __restrict__ fc_w,   const float* __restrict__ fc_b,
        const float* __restrict__ xyz_w,  const float* __restrict__ xyz_b,
        const float* __restrict__ wpqr_w, const float* __restrict__ wpqr_b,
        float* __restrict__ out) {
    int e = blockIdx.x;
    int t = threadIdx.x;
    int a0 = ei[e], a1 = ei[N_EDGES + e];
    int code = (min(a0, a1) << 3) + max(a0, a1);
    __shared__ float pl[CO];
    if (t < CO) pl[t] = pooled[(code << 6) + t] * (1.f / 4096.f);
    __syncthreads();

    float s[6] = {0.f, 0.f, 0.f, 0.f, 0.f, 0.f};
#pragma unroll
    for (int ff = 0; ff < 4; ++ff) {
        int f = ff * 256 + t;
        const float* wr = fc_w + f * CO;
        float d = fc_b[f];
#pragma unroll
        for (int c = 0; c < CO; ++c) d = fmaf(pl[c], wr[c], d);
        d = fmaxf(d, 0.f);
#pragma unroll
        for (int r = 0; r < 3; ++r) {
            s[r]     = fmaf(d, xyz_w[r * FEAT + f],  s[r]);
            s[3 + r] = fmaf(d, wpqr_w[r * FEAT + f], s[3 + r]);
        }
    }
#pragma unroll
    for (int r = 0; r < 6; ++r)
#pragma unroll
        for (int off = 32; off > 0; off >>= 1)
            s[r] += __shfl_down(s[r], off, 64);

    __shared__ float red[4][6];
    if ((t & 63) == 0) {
#pragma unroll
        for (int r = 0; r < 6; ++r) red[t >> 6][r] = s[r];
    }
    __syncthreads();
    if (t < 6) {
        float v = red[0][t] + red[1][t] + red[2][t] + red[3][t];
        v += (t < 3) ? xyz_b[t] : wpqr_b[t - 3];
        out[48 + e * 6 + t] = v;
        if (e < 8) out[e * 6 + t] = v;
    }
}

// ---------------------------------------------------------------------------
extern "C" void kernel_launch(void* const* d_in, const int* in_sizes, int n_in,
                              void* d_out, int out_size, void* d_ws, size_t ws_size,
                              hipStream_t stream) {
    const float* x        = (const float*)d_in[0];
    const int*   ei       = (const int*)d_in[1];
    const float* conv1_w  = (const float*)d_in[2];
    const float* bn_gamma = (const float*)d_in[3];
    const float* bn_beta  = (const float*)d_in[4];
    const float* bn_mean  = (const float*)d_in[5];
    const float* bn_var   = (const float*)d_in[6];
    const float* fc_w     = (const float*)d_in[7];
    const float* fc_b     = (const float*)d_in[8];
    const float* xyz_w    = (const float*)d_in[9];
    const float* xyz_b    = (const float*)d_in[10];
    const float* wpqr_w   = (const float*)d_in[11];
    const float* wpqr_b   = (const float*)d_in[12];
    float* out = (float*)d_out;

    char* ws = (char*)d_ws;
    float*          pooled = (float*)(ws + OFF_POOLED);
    unsigned short* wb2    = (unsigned short*)(ws + OFF_WB);
    float*          shiftb = (float*)(ws + OFF_SHIFT);
    unsigned short* A2     = (unsigned short*)(ws + OFF_A);
    unsigned short* B2     = (unsigned short*)(ws + OFF_B);

    repack_kernel<<<96, 256, 0, stream>>>(conv1_w, bn_gamma, bn_beta, bn_mean,
                                          bn_var, wb2, shiftb, pooled);
    conv_kernel<<<1024, 512, 0, stream>>>(x, wb2, shiftb, A2, B2);
    pool_kernel<<<1024, 256, 0, stream>>>(A2, B2, pooled);
    head_kernel<<<64, 256, 0, stream>>>(ei, pooled, fc_w, fc_b,
                                        xyz_w, xyz_b, wpqr_w, wpqr_b, out);
}